// Round 13
// baseline (158.409 us; speedup 1.0000x reference)
//
#include <hip/hip_runtime.h>

typedef __bf16 bf16x8 __attribute__((ext_vector_type(8)));
typedef unsigned short u16;
typedef unsigned short u16x8 __attribute__((ext_vector_type(8)));
typedef float f32x4 __attribute__((ext_vector_type(4)));

#define L_SEQ 2048
#define NQT   (L_SEQ / 128)
#define SB()  __builtin_amdgcn_sched_barrier(0)

__device__ __forceinline__ float bf2f(u16 x) {
    unsigned u = ((unsigned)x) << 16;
    return __builtin_bit_cast(float, u);
}
__device__ __forceinline__ u16 f2bf(float f) {
    unsigned u = __builtin_bit_cast(unsigned, f);
    u += 0x7FFFu + ((u >> 16) & 1u);
    return (u16)(u >> 16);
}

__device__ __forceinline__ void gload_lds16(const u16* g, u16* l) {
    __builtin_amdgcn_global_load_lds(
        (const __attribute__((address_space(1))) void*)g,
        (__attribute__((address_space(3))) void*)l, 16, 0, 0);
}

// f32 -> bf16 (RNE) for w_in, w_out (x is fused into gemm_qkv).
__global__ void cvt_w(const float* __restrict__ wi, const float* __restrict__ wo,
                      u16* __restrict__ wio, u16* __restrict__ woo,
                      int nwi8, int nwo8) {
    int i = blockIdx.x * blockDim.x + threadIdx.x;
    const float* src; u16* dst;
    if (i < nwi8) { src = wi; dst = wio; }
    else if (i < nwi8 + nwo8) { i -= nwi8; src = wo; dst = woo; }
    else return;
    const float4* p = reinterpret_cast<const float4*>(src) + (size_t)i * 2;
    const float4 a = p[0], b = p[1];
    u16x8 r;
    r[0] = f2bf(a.x); r[1] = f2bf(a.y); r[2] = f2bf(a.z); r[3] = f2bf(a.w);
    r[4] = f2bf(b.x); r[5] = f2bf(b.y); r[6] = f2bf(b.z); r[7] = f2bf(b.w);
    *(reinterpret_cast<u16x8*>(dst) + i) = r;
}

// ===== QKV GEMM with fused f32->bf16 A-conversion =====
// 256x128 tile, BK=32, ring-3 (72 KB), 8 waves. A read as f32 from x, converted
// in-register, written to LDS via conflict-free b128 pattern (thread t -> slots
// t and 512+t: byte 16*lane sweeps all 32 banks). B staged via gload_lds.
// Per iter t: frags(t); vmcnt(1) [A(t+1) landed; B(t+1) stays]; cvt+write A(t+1);
// issue A(t+2), B(t+2); vmcnt(5) [B(t+1) landed; 5 stay in flight]; barrier; MFMA.
__launch_bounds__(512, 4)
__global__ void gemm_qkv(const float* __restrict__ X, const u16* __restrict__ W,
                         const float* __restrict__ bias, u16* __restrict__ C,
                         int M, int N, int K) {
    __shared__ u16 As[3][256 * 32];
    __shared__ u16 Bs[3][128 * 32];

    const int tid   = threadIdx.x;
    const int lane  = tid & 63;
    const int wid   = tid >> 6;           // 0..7
    const int wm    = wid >> 1;           // 0..3 (m quarter)
    const int wn    = wid & 1;            // 0..1 (n half)
    const int row_l = lane & 15;
    const int grp   = lane >> 4;

    // XCD-aware bijective remap (nwg % 8 == 0)
    const int nwg  = gridDim.x * gridDim.y;
    const int hw   = blockIdx.y * gridDim.x + blockIdx.x;
    const int tile = (hw & 7) * (nwg >> 3) + (hw >> 3);
    const int m0 = (tile / gridDim.x) * 256;
    const int n0 = (tile % gridDim.x) * 128;

    // A staging (f32): thread t owns slot t (row t>>2) and slot 512+t (row +128),
    // chunk g = (t&3) ^ ((t>>3)&3)  [= read swizzle for both halves].
    const int ag  = (tid & 3) ^ ((tid >> 3) & 3);
    const float* gX0 = X + (size_t)(m0 + (tid >> 2)) * K + ag * 8;
    const float* gX1 = gX0 + (size_t)128 * K;
    u16* wA0 = &As[0][0] + tid * 8;          // + buf*8192 elements
    u16* wA1 = &As[0][0] + (512 + tid) * 8;

    // B staging (bf16 gload_lds): 1 issue = 128 rows x 32 cols (8 KB)
    const int brow = tid >> 2;
    const int bcol = ((tid & 3) ^ ((tid >> 3) & 3)) * 8;
    const u16* gB = W + (size_t)(n0 + brow) * K + bcol;

    f32x4 acc[4][4];
#pragma unroll
    for (int mi = 0; mi < 4; ++mi)
#pragma unroll
        for (int ni = 0; ni < 4; ++ni)
            acc[mi][ni] = (f32x4){0.f, 0.f, 0.f, 0.f};

    const int rchunk = (grp ^ ((row_l >> 1) & 3)) * 8;
    const int NT = K >> 5;                // 16

    // persistent A-prefetch registers (single set; loaded at t, written at t+1)
    f32x4 pa0, pa1, pa2, pa3;

    auto issueA = [&](int kt) {
        const f32x4* q0 = reinterpret_cast<const f32x4*>(gX0 + kt * 32);
        const f32x4* q1 = reinterpret_cast<const f32x4*>(gX1 + kt * 32);
        pa0 = q0[0]; pa1 = q0[1]; pa2 = q1[0]; pa3 = q1[1];
    };
    auto writeA = [&](int buf) {
        u16x8 w0, w1;
#pragma unroll
        for (int e = 0; e < 4; ++e) {
            w0[e] = f2bf(pa0[e]); w0[4 + e] = f2bf(pa1[e]);
            w1[e] = f2bf(pa2[e]); w1[4 + e] = f2bf(pa3[e]);
        }
        *reinterpret_cast<u16x8*>(wA0 + buf * 8192) = w0;
        *reinterpret_cast<u16x8*>(wA1 + buf * 8192) = w1;
    };

    // ---- prologue: A(0),B(0); write A(0); A(1),B(1); barrier ----
    issueA(0);
    SB();
    gload_lds16(gB, &Bs[0][0] + wid * 512);
    SB();
    asm volatile("s_waitcnt vmcnt(1)" ::: "memory");   // A(0) landed
    SB();
    writeA(0);
    SB();
    issueA(1);
    SB();
    gload_lds16(gB + 32, &Bs[1][0] + wid * 512);
    SB();
    asm volatile("s_waitcnt vmcnt(5)" ::: "memory");   // B(0) landed; A(1),B(1) in flight
    asm volatile("s_waitcnt lgkmcnt(0)" ::: "memory");
    __builtin_amdgcn_s_barrier();

    int buf = 0;
    for (int t = 0; t < NT; ++t) {
        // frags of tile t
        bf16x8 a[4], b[4];
#pragma unroll
        for (int mi = 0; mi < 4; ++mi)
            a[mi] = *reinterpret_cast<const bf16x8*>(
                &As[buf][(wm * 64 + mi * 16 + row_l) * 32 + rchunk]);
#pragma unroll
        for (int ni = 0; ni < 4; ++ni)
            b[ni] = *reinterpret_cast<const bf16x8*>(
                &Bs[buf][(wn * 64 + ni * 16 + row_l) * 32 + rchunk]);
        asm volatile("s_waitcnt lgkmcnt(0)" ::: "memory");  // frags in regs (WAR safe)
        SB();

        const int nxt = (buf + 1 < 3) ? buf + 1 : buf - 2;
        const int n2  = (buf + 2 < 3) ? buf + 2 : buf - 1;

        if (t + 1 < NT) {
            // A(t+1) landed? queue: [A(t+1)x4, B(t+1)]
            asm volatile("s_waitcnt vmcnt(1)" ::: "memory");
            SB();
            writeA(nxt);                                    // pa regs die here
            SB();
        }
        if (t + 2 < NT) {
            issueA(t + 2);                                  // reload pa regs
            SB();
            gload_lds16(gB + (size_t)(t + 2) * 32, &Bs[n2][0] + wid * 512);
            SB();
            // retire B(t+1); leave A(t+2)x4 + B(t+2) in flight
            asm volatile("s_waitcnt vmcnt(5)" ::: "memory");
        } else {
            asm volatile("s_waitcnt vmcnt(0)" ::: "memory");  // tail drain
        }
        asm volatile("s_waitcnt lgkmcnt(0)" ::: "memory");    // ds_writes visible
        if (t + 1 < NT) __builtin_amdgcn_s_barrier();
        SB();

        __builtin_amdgcn_s_setprio(1);
#pragma unroll
        for (int mi = 0; mi < 4; ++mi)
#pragma unroll
            for (int ni = 0; ni < 4; ++ni)
                acc[mi][ni] = __builtin_amdgcn_mfma_f32_16x16x32_bf16(a[mi], b[ni], acc[mi][ni], 0, 0, 0);
        __builtin_amdgcn_s_setprio(0);
        buf = nxt;
    }

#pragma unroll
    for (int ni = 0; ni < 4; ++ni) {
        const int col = n0 + wn * 64 + ni * 16 + row_l;
        const float bsf = bias[col];
#pragma unroll
        for (int mi = 0; mi < 4; ++mi) {
#pragma unroll
            for (int r = 0; r < 4; ++r) {
                const int rowm = m0 + wm * 64 + mi * 16 + grp * 4 + r;
                C[(size_t)rowm * N + col] = f2bf(acc[mi][ni][r] + bsf);
            }
        }
    }
}

// ===== out-proj GEMM: 256x128 bf16 ring-3 (round-11 structure, proven) =====
__launch_bounds__(512, 4)
__global__ void gemm_out(const u16* __restrict__ A, const u16* __restrict__ W,
                         const float* __restrict__ bias, float* __restrict__ Cv,
                         int M, int N, int K) {
    __shared__ u16 As[3][256 * 32];
    __shared__ u16 Bs[3][128 * 32];

    const int tid   = threadIdx.x;
    const int lane  = tid & 63;
    const int wid   = tid >> 6;
    const int wm    = wid >> 1;
    const int wn    = wid & 1;
    const int row_l = lane & 15;
    const int grp   = lane >> 4;

    const int nwg  = gridDim.x * gridDim.y;
    const int hw   = blockIdx.y * gridDim.x + blockIdx.x;
    const int tile = (hw & 7) * (nwg >> 3) + (hw >> 3);
    const int m0 = (tile / gridDim.x) * 256;
    const int n0 = (tile % gridDim.x) * 128;

    const int srow = tid >> 2;
    const int scol = ((tid & 3) ^ ((tid >> 3) & 3)) * 8;
    const u16* gA = A + (size_t)(m0 + srow) * K + scol;
    const u16* gB = W + (size_t)(n0 + srow) * K + scol;

    f32x4 acc[4][4];
#pragma unroll
    for (int mi = 0; mi < 4; ++mi)
#pragma unroll
        for (int ni = 0; ni < 4; ++ni)
            acc[mi][ni] = (f32x4){0.f, 0.f, 0.f, 0.f};

    auto stage = [&](int b2, int kt) {
        gload_lds16(gA + (size_t)kt * 32,                   &As[b2][0]    + wid * 512);
        gload_lds16(gA + (size_t)128 * K + (size_t)kt * 32, &As[b2][4096] + wid * 512);
        gload_lds16(gB + (size_t)kt * 32,                   &Bs[b2][0]    + wid * 512);
    };

    const int rchunk = (grp ^ ((row_l >> 1) & 3)) * 8;

    const int NT = K >> 5;
    stage(0, 0);
    stage(1, 1);
    asm volatile("s_waitcnt vmcnt(3)" ::: "memory");
    __builtin_amdgcn_s_barrier();

    int buf = 0;
    for (int kt = 0; kt < NT; ++kt) {
        bf16x8 a[4], b[4];
#pragma unroll
        for (int mi = 0; mi < 4; ++mi)
            a[mi] = *reinterpret_cast<const bf16x8*>(
                &As[buf][(wm * 64 + mi * 16 + row_l) * 32 + rchunk]);
#pragma unroll
        for (int ni = 0; ni < 4; ++ni)
            b[ni] = *reinterpret_cast<const bf16x8*>(
                &Bs[buf][(wn * 64 + ni * 16 + row_l) * 32 + rchunk]);

        if (kt + 2 < NT) {
            int st = buf + 2; if (st >= 3) st -= 3;
            stage(st, kt + 2);
        }
        if (kt < NT - 2)       asm volatile("s_waitcnt vmcnt(3)" ::: "memory");
        else if (kt == NT - 2) asm volatile("s_waitcnt vmcnt(0)" ::: "memory");
        __builtin_amdgcn_s_barrier();
        asm volatile("s_waitcnt lgkmcnt(0)" ::: "memory");
        __builtin_amdgcn_sched_barrier(0);
        __builtin_amdgcn_s_setprio(1);
#pragma unroll
        for (int mi = 0; mi < 4; ++mi)
#pragma unroll
            for (int ni = 0; ni < 4; ++ni)
                acc[mi][ni] = __builtin_amdgcn_mfma_f32_16x16x32_bf16(a[mi], b[ni], acc[mi][ni], 0, 0, 0);
        __builtin_amdgcn_s_setprio(0);
        __builtin_amdgcn_s_barrier();
        buf = buf + 1; if (buf >= 3) buf = 0;
    }

#pragma unroll
    for (int ni = 0; ni < 4; ++ni) {
        const int col = n0 + wn * 64 + ni * 16 + row_l;
        const float bsf = bias[col];
#pragma unroll
        for (int mi = 0; mi < 4; ++mi) {
#pragma unroll
            for (int r = 0; r < 4; ++r) {
                const int rowm = m0 + wm * 64 + mi * 16 + grp * 4 + r;
                Cv[(size_t)rowm * N + col] = acc[mi][ni][r] + bsf;
            }
        }
    }
}

// ===== banded local attention (round-9: Vt conflict-free swizzle + defer-max) =====
__launch_bounds__(512, 4)
__global__ void local_attn(const u16* __restrict__ qkv, u16* __restrict__ att) {
    __shared__ __align__(16) u16 Ks[256 * 64];
    __shared__ __align__(16) u16 Vt[64 * 256];
    __shared__ __align__(16) u16 Pl[8][512];

    const int tid   = threadIdx.x;
    const int lane  = tid & 63;
    const int wv    = tid >> 6;
    const int row_l = lane & 15;
    const int grp   = lane >> 4;
    const int qt = blockIdx.x, h = blockIdx.y, b = blockIdx.z;
    const int q0b = qt * 128;
    const int kstart = q0b - 64;
    const size_t base = (size_t)b * L_SEQ * 1536;
    const bool edge = (qt == 0) || (qt == NQT - 1);

    {
        const int r0 = tid >> 3;
        const int c  = tid & 7;
#pragma unroll
        for (int i = 0; i < 4; ++i) {
            const int row  = i * 64 + r0;
            const int keyg = min(max(kstart + row, 0), L_SEQ - 1);
            const int cg   = c ^ (row & 7);
            gload_lds16(qkv + base + (size_t)keyg * 1536 + 512 + h * 64 + cg * 8,
                        &Ks[i * 4096 + wv * 512]);
        }
    }
    {
#pragma unroll
        for (int i = 0; i < 4; ++i) {
            const int idx  = i * 512 + tid;
            const int row  = idx >> 3;
            const int c8   = idx & 7;
            const int keyg = min(max(kstart + row, 0), L_SEQ - 1);
            const u16x8 vu = *reinterpret_cast<const u16x8*>(
                qkv + base + (size_t)keyg * 1536 + 1024 + h * 64 + c8 * 8);
#pragma unroll
            for (int e = 0; e < 8; ++e) {
                const int d = c8 * 8 + e;
                const int slot = (row >> 3) ^ (d & 7) ^ ((d >> 3) & 7);
                Vt[d * 256 + slot * 8 + (row & 7)] = vu[e];
            }
        }
    }

    const int qrow_g = q0b + wv * 16 + row_l;
    const u16* qp = qkv + base + (size_t)qrow_g * 1536 + h * 64;
    const bf16x8 qf0 = *reinterpret_cast<const bf16x8*>(qp + grp * 8);
    const bf16x8 qf1 = *reinterpret_cast<const bf16x8*>(qp + 32 + grp * 8);

    __syncthreads();

    float m_r = -1e30f, l_r = 0.f;
    f32x4 acc[4];
#pragma unroll
    for (int ds = 0; ds < 4; ++ds) acc[ds] = (f32x4){0.f, 0.f, 0.f, 0.f};
    u16* Pw = Pl[wv];

    auto do_chunk = [&](int c, bool bandLo, bool bandHi, bool half, bool rng) {
        const int kcL = wv * 16 + 32 * c;
        const int kcG = kstart + kcL;
        const int nf = half ? 1 : 2;

        f32x4 s[2];
#pragma unroll
        for (int f = 0; f < 2; ++f) {
            if (f >= nf) break;
            const int rr = kcL + 16 * f + row_l;
            const bf16x8 ka = *reinterpret_cast<const bf16x8*>(
                &Ks[rr * 64 + ((grp ^ (rr & 7)) * 8)]);
            const bf16x8 kb = *reinterpret_cast<const bf16x8*>(
                &Ks[rr * 64 + (((grp + 4) ^ (rr & 7)) * 8)]);
            f32x4 z = (f32x4){0.f, 0.f, 0.f, 0.f};
            z = __builtin_amdgcn_mfma_f32_16x16x32_bf16(ka, qf0, z, 0, 0, 0);
            z = __builtin_amdgcn_mfma_f32_16x16x32_bf16(kb, qf1, z, 0, 0, 0);
            s[f] = z;
        }

        float p[2][4];
        float cmax = -1e30f;
#pragma unroll
        for (int f = 0; f < 2; ++f) {
            if (f >= nf) break;
#pragma unroll
            for (int r = 0; r < 4; ++r) {
                const int k = 16 * f + grp * 4 + r;
                bool ok = true;
                if (bandLo) ok = ok && (k >= row_l);
                if (bandHi) ok = ok && (k <= row_l);
                if (rng) { const int kg = kcG + k; ok = ok && (kg >= 0) && (kg < L_SEQ); }
                const float sv = ok ? s[f][r] * 0.125f : -1e30f;
                p[f][r] = sv;
                cmax = fmaxf(cmax, sv);
            }
        }
        cmax = fmaxf(cmax, __shfl_xor(cmax, 16, 64));
        cmax = fmaxf(cmax, __shfl_xor(cmax, 32, 64));

        const bool need = !__all(cmax <= m_r + 8.f);
        float mu;
        float scl = 1.f;
        if (need) {
            const float mn = fmaxf(m_r, cmax);
            scl = __expf(m_r - mn);
            m_r = mn;
            mu  = mn;
        } else {
            mu = m_r;
        }

        float lsum = 0.f;
#pragma unroll
        for (int f = 0; f < 2; ++f) {
            if (f >= nf) break;
#pragma unroll
            for (int r = 0; r < 4; ++r) {
                const float pv = (p[f][r] <= -1e29f) ? 0.f : __expf(p[f][r] - mu);
                p[f][r] = pv;
                lsum += pv;
            }
        }
        lsum += __shfl_xor(lsum, 16, 64);
        lsum += __shfl_xor(lsum, 32, 64);
        l_r = l_r * scl + lsum;

        if (need) {
            float scl4[4];
#pragma unroll
            for (int r = 0; r < 4; ++r) scl4[r] = __shfl(scl, grp * 4 + r, 64);
#pragma unroll
            for (int ds = 0; ds < 4; ++ds)
#pragma unroll
                for (int r = 0; r < 4; ++r) acc[ds][r] *= scl4[r];
        }

#pragma unroll
        for (int f = 0; f < 2; ++f)
#pragma unroll
            for (int r = 0; r < 4; ++r) {
                const int k = 16 * f + grp * 4 + r;
                const int slot = (k >> 3) ^ ((row_l >> 1) & 3);
                const float pv = (f < nf) ? p[f][r] : 0.f;
                Pw[row_l * 32 + slot * 8 + (k & 7)] = f2bf(pv);
            }
        const bf16x8 pa = *reinterpret_cast<const bf16x8*>(
            &Pw[row_l * 32 + ((grp ^ ((row_l >> 1) & 3)) * 8)]);

        int k0 = kcL + grp * 8;
        if (half) k0 = min(k0, 248);
#pragma unroll
        for (int ds = 0; ds < 4; ++ds) {
            const int d = ds * 16 + row_l;
            const int slot = (k0 >> 3) ^ (d & 7) ^ ((d >> 3) & 7);
            const bf16x8 vf = *reinterpret_cast<const bf16x8*>(
                &Vt[d * 256 + slot * 8]);
            acc[ds] = __builtin_amdgcn_mfma_f32_16x16x32_bf16(pa, vf, acc[ds], 0, 0, 0);
        }
    };

    if (!edge) {
        do_chunk(0, true,  false, false, false);
        do_chunk(1, false, false, false, false);
        do_chunk(2, false, false, false, false);
        do_chunk(3, false, false, false, false);
        do_chunk(4, false, true,  true,  false);
    } else {
        const int kw = kstart + wv * 16;
        if (kw       > -32 && kw       < L_SEQ) do_chunk(0, true,  false, false, true);
        if (kw + 32  > -32 && kw + 32  < L_SEQ) do_chunk(1, false, false, false, true);
        if (kw + 64  > -32 && kw + 64  < L_SEQ) do_chunk(2, false, false, false, true);
        if (kw + 96  > -32 && kw + 96  < L_SEQ) do_chunk(3, false, false, false, true);
        if (kw + 128 > -32 && kw + 128 < L_SEQ) do_chunk(4, false, true,  true,  true);
    }

    const float inv = 1.f / l_r;
    float inv4[4];
#pragma unroll
    for (int r = 0; r < 4; ++r) inv4[r] = __shfl(inv, grp * 4 + r, 64);
    const int qg = q0b + wv * 16 + grp * 4;
#pragma unroll
    for (int r = 0; r < 4; ++r)
#pragma unroll
        for (int ds = 0; ds < 4; ++ds)
            att[(size_t)(b * L_SEQ + qg + r) * 512 + h * 64 + ds * 16 + row_l] =
                f2bf(acc[ds][r] * inv4[r]);
}

extern "C" void kernel_launch(void* const* d_in, const int* in_sizes, int n_in,
                              void* d_out, int out_size, void* d_ws, size_t ws_size,
                              hipStream_t stream) {
    const float* x     = (const float*)d_in[0];
    const float* w_in  = (const float*)d_in[1];
    const float* b_in  = (const float*)d_in[2];
    const float* w_out = (const float*)d_in[3];
    const float* b_out = (const float*)d_in[4];
    float* out = (float*)d_out;

    const int B = 8, L = L_SEQ;
    const int M = B * L;  // 16384

    u16* qkv   = (u16*)d_ws;                      // [M, 1536]  bf16
    u16* att   = qkv   + (size_t)M * 1536;        // [M, 512]   bf16
    u16* wi_bf = att   + (size_t)M * 512;         // [1536, 512] bf16
    u16* wo_bf = wi_bf + (size_t)1536 * 512;      // [512, 512] bf16

    const int nwi8 = 1536 * 512 / 8;
    const int nwo8 = 512 * 512 / 8;
    const int ncvt = nwi8 + nwo8;
    cvt_w<<<(ncvt + 255) / 256, 256, 0, stream>>>(w_in, w_out, wi_bf, wo_bf, nwi8, nwo8);

    // QKV projection: reads x (f32) directly, cvt fused into A-staging
    gemm_qkv<<<dim3(1536 / 128, M / 256), dim3(512), 0, stream>>>(
        x, wi_bf, b_in, qkv, M, 1536, 512);

    local_attn<<<dim3(NQT, 8, B), dim3(512), 0, stream>>>(qkv, att);

    gemm_out<<<dim3(512 / 128, M / 256), dim3(512), 0, stream>>>(
        att, wo_bf, b_out, out, M, 512, 512);
}

// Round 14
// 87.028 us; speedup vs baseline: 1.8202x; 1.8202x over previous
//
#include <hip/hip_runtime.h>

typedef __bf16 bf16x8 __attribute__((ext_vector_type(8)));
typedef unsigned short u16;
typedef unsigned short u16x8 __attribute__((ext_vector_type(8)));
typedef float f32x4 __attribute__((ext_vector_type(4)));

#define L_SEQ 2048
#define NQT   (L_SEQ / 128)

__device__ __forceinline__ float bf2f(u16 x) {
    unsigned u = ((unsigned)x) << 16;
    return __builtin_bit_cast(float, u);
}
__device__ __forceinline__ u16 f2bf(float f) {
    unsigned u = __builtin_bit_cast(unsigned, f);
    u += 0x7FFFu + ((u >> 16) & 1u);
    return (u16)(u >> 16);
}

__device__ __forceinline__ void gload_lds16(const u16* g, u16* l) {
    __builtin_amdgcn_global_load_lds(
        (const __attribute__((address_space(1))) void*)g,
        (__attribute__((address_space(3))) void*)l, 16, 0, 0);
}

// f32 -> bf16 (RNE) for x, w_in, w_out in one launch. Sizes in 8-element units.
__global__ void cvt_all(const float* __restrict__ x, const float* __restrict__ wi,
                        const float* __restrict__ wo, u16* __restrict__ xo,
                        u16* __restrict__ wio, u16* __restrict__ woo,
                        int nx8, int nwi8, int nwo8) {
    int i = blockIdx.x * blockDim.x + threadIdx.x;
    const float* src; u16* dst;
    if (i < nx8) { src = x; dst = xo; }
    else if (i < nx8 + nwi8) { i -= nx8; src = wi; dst = wio; }
    else if (i < nx8 + nwi8 + nwo8) { i -= nx8 + nwi8; src = wo; dst = woo; }
    else return;
    const float4* p = reinterpret_cast<const float4*>(src) + (size_t)i * 2;
    const float4 a = p[0], b = p[1];
    u16x8 r;
    r[0] = f2bf(a.x); r[1] = f2bf(a.y); r[2] = f2bf(a.z); r[3] = f2bf(a.w);
    r[4] = f2bf(b.x); r[5] = f2bf(b.y); r[6] = f2bf(b.z); r[7] = f2bf(b.w);
    *(reinterpret_cast<u16x8*>(dst) + i) = r;
}

// ===== QKV GEMM: 256x128 tile, BK=32, ring-3 (72 KB), 8 waves (round-8 proven) =====
__launch_bounds__(512, 4)
__global__ void gemm_qkv(const u16* __restrict__ A, const u16* __restrict__ W,
                         const float* __restrict__ bias, u16* __restrict__ C,
                         int M, int N, int K) {
    __shared__ u16 As[3][256 * 32];
    __shared__ u16 Bs[3][128 * 32];

    const int tid   = threadIdx.x;
    const int lane  = tid & 63;
    const int wid   = tid >> 6;           // 0..7
    const int wm    = wid >> 1;           // 0..3 (m quarter)
    const int wn    = wid & 1;            // 0..1 (n half)
    const int row_l = lane & 15;
    const int grp   = lane >> 4;

    const int nwg  = gridDim.x * gridDim.y;
    const int hw   = blockIdx.y * gridDim.x + blockIdx.x;
    const int tile = (hw & 7) * (nwg >> 3) + (hw >> 3);
    const int m0 = (tile / gridDim.x) * 256;
    const int n0 = (tile % gridDim.x) * 128;

    const int srow = tid >> 2;                       // 0..127
    const int scol = ((tid & 3) ^ ((tid >> 3) & 3)) * 8;
    const u16* gA = A + (size_t)(m0 + srow) * K + scol;
    const u16* gB = W + (size_t)(n0 + srow) * K + scol;

    f32x4 acc[4][4];
#pragma unroll
    for (int mi = 0; mi < 4; ++mi)
#pragma unroll
        for (int ni = 0; ni < 4; ++ni)
            acc[mi][ni] = (f32x4){0.f, 0.f, 0.f, 0.f};

    auto stage = [&](int buf, int kt) {
        gload_lds16(gA + (size_t)kt * 32,                   &As[buf][0]    + wid * 512);
        gload_lds16(gA + (size_t)128 * K + (size_t)kt * 32, &As[buf][4096] + wid * 512);
        gload_lds16(gB + (size_t)kt * 32,                   &Bs[buf][0]    + wid * 512);
    };

    const int rchunk = (grp ^ ((row_l >> 1) & 3)) * 8;

    const int NT = K >> 5;                // 16
    stage(0, 0);
    stage(1, 1);
    asm volatile("s_waitcnt vmcnt(3)" ::: "memory");
    __builtin_amdgcn_s_barrier();

    int buf = 0;
    for (int kt = 0; kt < NT; ++kt) {
        bf16x8 a[4], b[4];
#pragma unroll
        for (int mi = 0; mi < 4; ++mi)
            a[mi] = *reinterpret_cast<const bf16x8*>(
                &As[buf][(wm * 64 + mi * 16 + row_l) * 32 + rchunk]);
#pragma unroll
        for (int ni = 0; ni < 4; ++ni)
            b[ni] = *reinterpret_cast<const bf16x8*>(
                &Bs[buf][(wn * 64 + ni * 16 + row_l) * 32 + rchunk]);

        if (kt + 2 < NT) {
            int st = buf + 2; if (st >= 3) st -= 3;
            stage(st, kt + 2);
        }
        if (kt < NT - 2)       asm volatile("s_waitcnt vmcnt(3)" ::: "memory");
        else if (kt == NT - 2) asm volatile("s_waitcnt vmcnt(0)" ::: "memory");
        __builtin_amdgcn_s_barrier();
        asm volatile("s_waitcnt lgkmcnt(0)" ::: "memory");
        __builtin_amdgcn_sched_barrier(0);
        __builtin_amdgcn_s_setprio(1);
#pragma unroll
        for (int mi = 0; mi < 4; ++mi)
#pragma unroll
            for (int ni = 0; ni < 4; ++ni)
                acc[mi][ni] = __builtin_amdgcn_mfma_f32_16x16x32_bf16(a[mi], b[ni], acc[mi][ni], 0, 0, 0);
        __builtin_amdgcn_s_setprio(0);
        __builtin_amdgcn_s_barrier();
        buf = buf + 1; if (buf >= 3) buf = 0;
    }

#pragma unroll
    for (int ni = 0; ni < 4; ++ni) {
        const int col = n0 + wn * 64 + ni * 16 + row_l;
        const float bsf = bias[col];
#pragma unroll
        for (int mi = 0; mi < 4; ++mi) {
#pragma unroll
            for (int r = 0; r < 4; ++r) {
                const int rowm = m0 + wm * 64 + mi * 16 + grp * 4 + r;
                C[(size_t)rowm * N + col] = f2bf(acc[mi][ni][r] + bsf);
            }
        }
    }
}

// ===== out-proj GEMM: ring-3 128x128 (round-7 proven) =====
__launch_bounds__(256, 3)
__global__ void gemm_ring(const u16* __restrict__ A, const u16* __restrict__ W,
                          const float* __restrict__ bias, float* __restrict__ Cv,
                          int M, int N, int K) {
    __shared__ u16 As[3][128 * 32];
    __shared__ u16 Bs[3][128 * 32];

    const int tid   = threadIdx.x;
    const int lane  = tid & 63;
    const int wid   = tid >> 6;
    const int wm    = wid >> 1;
    const int wn    = wid & 1;
    const int row_l = lane & 15;
    const int grp   = lane >> 4;

    const int nwg  = gridDim.x * gridDim.y;
    const int hw   = blockIdx.y * gridDim.x + blockIdx.x;
    const int tile = (hw & 7) * (nwg >> 3) + (hw >> 3);
    const int m0 = (tile / gridDim.x) * 128;
    const int n0 = (tile % gridDim.x) * 128;

    const int srow = tid >> 2;
    const int scol = ((tid & 3) ^ ((tid >> 3) & 3)) * 8;
    const u16* gA = A + (size_t)(m0 + srow) * K + scol;
    const u16* gB = W + (size_t)(n0 + srow) * K + scol;

    f32x4 acc[4][4];
#pragma unroll
    for (int mi = 0; mi < 4; ++mi)
#pragma unroll
        for (int ni = 0; ni < 4; ++ni)
            acc[mi][ni] = (f32x4){0.f, 0.f, 0.f, 0.f};

    auto stage = [&](int buf, int kt) {
#pragma unroll
        for (int i = 0; i < 2; ++i) {
            gload_lds16(gA + (size_t)(i * 64) * K + kt * 32, &As[buf][i * 2048 + wid * 512]);
            gload_lds16(gB + (size_t)(i * 64) * K + kt * 32, &Bs[buf][i * 2048 + wid * 512]);
        }
    };

    const int rchunk = (grp ^ ((row_l >> 1) & 3)) * 8;

    auto compute = [&](int buf) {
        bf16x8 a[4], b[4];
#pragma unroll
        for (int mi = 0; mi < 4; ++mi)
            a[mi] = *reinterpret_cast<const bf16x8*>(
                &As[buf][(wm * 64 + mi * 16 + row_l) * 32 + rchunk]);
#pragma unroll
        for (int ni = 0; ni < 4; ++ni)
            b[ni] = *reinterpret_cast<const bf16x8*>(
                &Bs[buf][(wn * 64 + ni * 16 + row_l) * 32 + rchunk]);
        __builtin_amdgcn_s_setprio(1);
#pragma unroll
        for (int mi = 0; mi < 4; ++mi)
#pragma unroll
            for (int ni = 0; ni < 4; ++ni)
                acc[mi][ni] = __builtin_amdgcn_mfma_f32_16x16x32_bf16(a[mi], b[ni], acc[mi][ni], 0, 0, 0);
        __builtin_amdgcn_s_setprio(0);
    };

    const int NT = K >> 5;
    stage(0, 0);
    stage(1, 1);
    int cur = 0;
    for (int t = 0; t < NT; ++t) {
        if (t == NT - 1) asm volatile("s_waitcnt vmcnt(0)" ::: "memory");
        else             asm volatile("s_waitcnt vmcnt(4)" ::: "memory");
        __builtin_amdgcn_s_barrier();
        if (t + 2 < NT) {
            int st = cur + 2; if (st >= 3) st -= 3;
            stage(st, t + 2);
        }
        compute(cur);
        cur = cur + 1; if (cur >= 3) cur = 0;
    }

#pragma unroll
    for (int ni = 0; ni < 4; ++ni) {
        const int col = n0 + wn * 64 + ni * 16 + row_l;
        const float bsf = bias[col];
#pragma unroll
        for (int mi = 0; mi < 4; ++mi) {
#pragma unroll
            for (int r = 0; r < 4; ++r) {
                const int rowm = m0 + wm * 64 + mi * 16 + grp * 4 + r;
                Cv[(size_t)rowm * N + col] = acc[mi][ni][r] + bsf;
            }
        }
    }
}

// ===== banded local attention (round-9: Vt conflict-free swizzle + defer-max) =====
__launch_bounds__(512, 4)
__global__ void local_attn(const u16* __restrict__ qkv, u16* __restrict__ att) {
    __shared__ __align__(16) u16 Ks[256 * 64];
    __shared__ __align__(16) u16 Vt[64 * 256];
    __shared__ __align__(16) u16 Pl[8][512];

    const int tid   = threadIdx.x;
    const int lane  = tid & 63;
    const int wv    = tid >> 6;
    const int row_l = lane & 15;
    const int grp   = lane >> 4;
    const int qt = blockIdx.x, h = blockIdx.y, b = blockIdx.z;
    const int q0b = qt * 128;
    const int kstart = q0b - 64;
    const size_t base = (size_t)b * L_SEQ * 1536;
    const bool edge = (qt == 0) || (qt == NQT - 1);

    {
        const int r0 = tid >> 3;
        const int c  = tid & 7;
#pragma unroll
        for (int i = 0; i < 4; ++i) {
            const int row  = i * 64 + r0;
            const int keyg = min(max(kstart + row, 0), L_SEQ - 1);
            const int cg   = c ^ (row & 7);
            gload_lds16(qkv + base + (size_t)keyg * 1536 + 512 + h * 64 + cg * 8,
                        &Ks[i * 4096 + wv * 512]);
        }
    }
    {
#pragma unroll
        for (int i = 0; i < 4; ++i) {
            const int idx  = i * 512 + tid;
            const int row  = idx >> 3;
            const int c8   = idx & 7;
            const int keyg = min(max(kstart + row, 0), L_SEQ - 1);
            const u16x8 vu = *reinterpret_cast<const u16x8*>(
                qkv + base + (size_t)keyg * 1536 + 1024 + h * 64 + c8 * 8);
#pragma unroll
            for (int e = 0; e < 8; ++e) {
                const int d = c8 * 8 + e;
                const int slot = (row >> 3) ^ (d & 7) ^ ((d >> 3) & 7);
                Vt[d * 256 + slot * 8 + (row & 7)] = vu[e];
            }
        }
    }

    const int qrow_g = q0b + wv * 16 + row_l;
    const u16* qp = qkv + base + (size_t)qrow_g * 1536 + h * 64;
    const bf16x8 qf0 = *reinterpret_cast<const bf16x8*>(qp + grp * 8);
    const bf16x8 qf1 = *reinterpret_cast<const bf16x8*>(qp + 32 + grp * 8);

    __syncthreads();

    float m_r = -1e30f, l_r = 0.f;
    f32x4 acc[4];
#pragma unroll
    for (int ds = 0; ds < 4; ++ds) acc[ds] = (f32x4){0.f, 0.f, 0.f, 0.f};
    u16* Pw = Pl[wv];

    auto do_chunk = [&](int c, bool bandLo, bool bandHi, bool half, bool rng) {
        const int kcL = wv * 16 + 32 * c;
        const int kcG = kstart + kcL;
        const int nf = half ? 1 : 2;

        f32x4 s[2];
#pragma unroll
        for (int f = 0; f < 2; ++f) {
            if (f >= nf) break;
            const int rr = kcL + 16 * f + row_l;
            const bf16x8 ka = *reinterpret_cast<const bf16x8*>(
                &Ks[rr * 64 + ((grp ^ (rr & 7)) * 8)]);
            const bf16x8 kb = *reinterpret_cast<const bf16x8*>(
                &Ks[rr * 64 + (((grp + 4) ^ (rr & 7)) * 8)]);
            f32x4 z = (f32x4){0.f, 0.f, 0.f, 0.f};
            z = __builtin_amdgcn_mfma_f32_16x16x32_bf16(ka, qf0, z, 0, 0, 0);
            z = __builtin_amdgcn_mfma_f32_16x16x32_bf16(kb, qf1, z, 0, 0, 0);
            s[f] = z;
        }

        float p[2][4];
        float cmax = -1e30f;
#pragma unroll
        for (int f = 0; f < 2; ++f) {
            if (f >= nf) break;
#pragma unroll
            for (int r = 0; r < 4; ++r) {
                const int k = 16 * f + grp * 4 + r;
                bool ok = true;
                if (bandLo) ok = ok && (k >= row_l);
                if (bandHi) ok = ok && (k <= row_l);
                if (rng) { const int kg = kcG + k; ok = ok && (kg >= 0) && (kg < L_SEQ); }
                const float sv = ok ? s[f][r] * 0.125f : -1e30f;
                p[f][r] = sv;
                cmax = fmaxf(cmax, sv);
            }
        }
        cmax = fmaxf(cmax, __shfl_xor(cmax, 16, 64));
        cmax = fmaxf(cmax, __shfl_xor(cmax, 32, 64));

        const bool need = !__all(cmax <= m_r + 8.f);
        float mu;
        float scl = 1.f;
        if (need) {
            const float mn = fmaxf(m_r, cmax);
            scl = __expf(m_r - mn);
            m_r = mn;
            mu  = mn;
        } else {
            mu = m_r;
        }

        float lsum = 0.f;
#pragma unroll
        for (int f = 0; f < 2; ++f) {
            if (f >= nf) break;
#pragma unroll
            for (int r = 0; r < 4; ++r) {
                const float pv = (p[f][r] <= -1e29f) ? 0.f : __expf(p[f][r] - mu);
                p[f][r] = pv;
                lsum += pv;
            }
        }
        lsum += __shfl_xor(lsum, 16, 64);
        lsum += __shfl_xor(lsum, 32, 64);
        l_r = l_r * scl + lsum;

        if (need) {
            float scl4[4];
#pragma unroll
            for (int r = 0; r < 4; ++r) scl4[r] = __shfl(scl, grp * 4 + r, 64);
#pragma unroll
            for (int ds = 0; ds < 4; ++ds)
#pragma unroll
                for (int r = 0; r < 4; ++r) acc[ds][r] *= scl4[r];
        }

#pragma unroll
        for (int f = 0; f < 2; ++f)
#pragma unroll
            for (int r = 0; r < 4; ++r) {
                const int k = 16 * f + grp * 4 + r;
                const int slot = (k >> 3) ^ ((row_l >> 1) & 3);
                const float pv = (f < nf) ? p[f][r] : 0.f;
                Pw[row_l * 32 + slot * 8 + (k & 7)] = f2bf(pv);
            }
        const bf16x8 pa = *reinterpret_cast<const bf16x8*>(
            &Pw[row_l * 32 + ((grp ^ ((row_l >> 1) & 3)) * 8)]);

        int k0 = kcL + grp * 8;
        if (half) k0 = min(k0, 248);
#pragma unroll
        for (int ds = 0; ds < 4; ++ds) {
            const int d = ds * 16 + row_l;
            const int slot = (k0 >> 3) ^ (d & 7) ^ ((d >> 3) & 7);
            const bf16x8 vf = *reinterpret_cast<const bf16x8*>(
                &Vt[d * 256 + slot * 8]);
            acc[ds] = __builtin_amdgcn_mfma_f32_16x16x32_bf16(pa, vf, acc[ds], 0, 0, 0);
        }
    };

    if (!edge) {
        do_chunk(0, true,  false, false, false);
        do_chunk(1, false, false, false, false);
        do_chunk(2, false, false, false, false);
        do_chunk(3, false, false, false, false);
        do_chunk(4, false, true,  true,  false);
    } else {
        const int kw = kstart + wv * 16;
        if (kw       > -32 && kw       < L_SEQ) do_chunk(0, true,  false, false, true);
        if (kw + 32  > -32 && kw + 32  < L_SEQ) do_chunk(1, false, false, false, true);
        if (kw + 64  > -32 && kw + 64  < L_SEQ) do_chunk(2, false, false, false, true);
        if (kw + 96  > -32 && kw + 96  < L_SEQ) do_chunk(3, false, false, false, true);
        if (kw + 128 > -32 && kw + 128 < L_SEQ) do_chunk(4, false, true,  true,  true);
    }

    const float inv = 1.f / l_r;
    float inv4[4];
#pragma unroll
    for (int r = 0; r < 4; ++r) inv4[r] = __shfl(inv, grp * 4 + r, 64);
    const int qg = q0b + wv * 16 + grp * 4;
#pragma unroll
    for (int r = 0; r < 4; ++r)
#pragma unroll
        for (int ds = 0; ds < 4; ++ds)
            att[(size_t)(b * L_SEQ + qg + r) * 512 + h * 64 + ds * 16 + row_l] =
                f2bf(acc[ds][r] * inv4[r]);
}

extern "C" void kernel_launch(void* const* d_in, const int* in_sizes, int n_in,
                              void* d_out, int out_size, void* d_ws, size_t ws_size,
                              hipStream_t stream) {
    const float* x     = (const float*)d_in[0];
    const float* w_in  = (const float*)d_in[1];
    const float* b_in  = (const float*)d_in[2];
    const float* w_out = (const float*)d_in[3];
    const float* b_out = (const float*)d_in[4];
    float* out = (float*)d_out;

    const int B = 8, L = L_SEQ;
    const int M = B * L;  // 16384

    u16* qkv   = (u16*)d_ws;                      // [M, 1536]  bf16
    u16* att   = qkv   + (size_t)M * 1536;        // [M, 512]   bf16
    u16* x_bf  = att   + (size_t)M * 512;         // [M, 512]   bf16
    u16* wi_bf = x_bf  + (size_t)M * 512;         // [1536, 512] bf16
    u16* wo_bf = wi_bf + (size_t)1536 * 512;      // [512, 512] bf16

    const int nx8  = M * 512 / 8;
    const int nwi8 = 1536 * 512 / 8;
    const int nwo8 = 512 * 512 / 8;
    const int ncvt = nx8 + nwi8 + nwo8;
    cvt_all<<<(ncvt + 255) / 256, 256, 0, stream>>>(x, w_in, w_out, x_bf, wi_bf, wo_bf,
                                                    nx8, nwi8, nwo8);

    // QKV projection: 256x128 tile, 8 waves, ring-3 counted-vmcnt (round-8 proven)
    gemm_qkv<<<dim3(1536 / 128, M / 256), dim3(512), 0, stream>>>(
        x_bf, wi_bf, b_in, qkv, M, 1536, 512);

    local_attn<<<dim3(NQT, 8, B), dim3(512), 0, stream>>>(qkv, att);

    // out-proj: ring-3 128x128 (round-7 proven, f32 out)
    gemm_ring<<<dim3(512 / 128, M / 128), dim3(256), 0, stream>>>(
        att, wo_bf, b_out, out, M, 512, 512);
}